// Round 2
// baseline (278.170 us; speedup 1.0000x reference)
//
#include <hip/hip_runtime.h>
#include <math.h>

#define VOCAB 50257
#define DIM 768
#define RANK 16
#define SCALING 2.0f   // ALPHA / RANK = 32/16

constexpr int P1_BLOCKS = 2048;
constexpr int P1_THREADS = 192;                                     // 3 waves; thread owns 4 cols
constexpr int ROWS_PER_BLOCK = (VOCAB + P1_BLOCKS - 1) / P1_BLOCKS; // 25

constexpr int RED_THREADS = 1024;
constexpr int RED_WAVES = RED_THREADS / 64;   // 16
constexpr int RED_BLOCKS = DIM / 64;          // 12 blocks, 64 columns each

constexpr int TOKENS_PER_BLOCK = 4;
constexpr int G_THREADS = 192;

// ---------------- Pass 1: per-block partial column sum-of-squares ----------------
// partials[P1_BLOCKS][DIM] row-major; every slot written (zeros for empty tail blocks).
// Register double-buffer: row v+1's emb load + A-row scalar load issue before row v's FMAs.
__global__ __launch_bounds__(P1_THREADS, 4) void dora_pass1(
    const float* __restrict__ emb, const float* __restrict__ lora_a,
    const float* __restrict__ lora_b, float* __restrict__ partials) {
  const int t = threadIdx.x;
  const int c4 = t * 4;

  float4 B[RANK];  // B[:, c4..c4+3] — 64 VGPRs, reused for all 25 rows
#pragma unroll
  for (int k = 0; k < RANK; ++k)
    B[k] = *reinterpret_cast<const float4*>(lora_b + k * DIM + c4);

  const int r0 = blockIdx.x * ROWS_PER_BLOCK;
  const int r1 = min(r0 + ROWS_PER_BLOCK, VOCAB);
  float4 acc = make_float4(0.f, 0.f, 0.f, 0.f);

  if (r0 < r1) {
    float4 e = *reinterpret_cast<const float4*>(emb + (size_t)r0 * DIM + c4);
    float a[RANK];  // wave-uniform address -> scalar loads
#pragma unroll
    for (int k = 0; k < RANK; ++k) a[k] = lora_a[(size_t)r0 * RANK + k];

    for (int v = r0; v < r1; ++v) {
      const int vp = min(v + 1, r1 - 1);  // clamped prefetch (no OOB; last is redundant L1 hit)
      const float4 e_next = *reinterpret_cast<const float4*>(emb + (size_t)vp * DIM + c4);
      float a_next[RANK];
#pragma unroll
      for (int k = 0; k < RANK; ++k) a_next[k] = lora_a[(size_t)vp * RANK + k];

      float dx = 0.f, dy = 0.f, dz = 0.f, dw = 0.f;
#pragma unroll
      for (int k = 0; k < RANK; ++k) {
        dx = fmaf(a[k], B[k].x, dx);
        dy = fmaf(a[k], B[k].y, dy);
        dz = fmaf(a[k], B[k].z, dz);
        dw = fmaf(a[k], B[k].w, dw);
      }
      const float cx = fmaf(SCALING, dx, e.x);
      const float cy = fmaf(SCALING, dy, e.y);
      const float cz = fmaf(SCALING, dz, e.z);
      const float cw = fmaf(SCALING, dw, e.w);
      acc.x = fmaf(cx, cx, acc.x);
      acc.y = fmaf(cy, cy, acc.y);
      acc.z = fmaf(cz, cz, acc.z);
      acc.w = fmaf(cw, cw, acc.w);

      e = e_next;
#pragma unroll
      for (int k = 0; k < RANK; ++k) a[k] = a_next[k];
    }
  }
  *reinterpret_cast<float4*>(partials + (size_t)blockIdx.x * DIM + c4) = acc;
}

// ---------------- Reduce: block owns 64 consecutive columns (coalesced) ----------------
__global__ __launch_bounds__(RED_THREADS) void dora_reduce(
    const float* __restrict__ partials, const float* __restrict__ magnitude,
    float* __restrict__ scale) {
  const int lane = threadIdx.x & 63;
  const int w = threadIdx.x >> 6;            // wave id 0..15
  const int c = blockIdx.x * 64 + lane;      // consecutive lanes -> consecutive columns

  float s = 0.f;
#pragma unroll 8
  for (int r = w; r < P1_BLOCKS; r += RED_WAVES)   // 128 rows/thread, 256 B/wave-load
    s += partials[(size_t)r * DIM + c];

  __shared__ float lds[RED_WAVES][64];
  lds[w][lane] = s;
  __syncthreads();
  if (w == 0) {
    float tot = 0.f;
#pragma unroll
    for (int i = 0; i < RED_WAVES; ++i) tot += lds[i][lane];
    const float norm = fmaxf(sqrtf(tot), 1e-8f);
    scale[c] = magnitude[c] / norm;
  }
}

// ---------------- Gather: 4 tokens/block, e-row + A-row prefetch, B in registers ----------------
__global__ __launch_bounds__(G_THREADS, 4) void dora_gather(
    const int* __restrict__ tokens, const float* __restrict__ emb,
    const float* __restrict__ lora_a, const float* __restrict__ lora_b,
    const float* __restrict__ scale, float* __restrict__ out, int n_tokens) {
  const int t = threadIdx.x;
  const int c4 = t * 4;

  float4 B[RANK];
#pragma unroll
  for (int k = 0; k < RANK; ++k)
    B[k] = *reinterpret_cast<const float4*>(lora_b + k * DIM + c4);
  const float4 sc = *reinterpret_cast<const float4*>(scale + c4);

  const int tok0 = blockIdx.x * TOKENS_PER_BLOCK;
  int id[TOKENS_PER_BLOCK];                     // uniform -> scalar loads
#pragma unroll
  for (int i = 0; i < TOKENS_PER_BLOCK; ++i)
    id[i] = tokens[min(tok0 + i, n_tokens - 1)];

  float4 e = *reinterpret_cast<const float4*>(emb + (size_t)id[0] * DIM + c4);
  float a[RANK];
#pragma unroll
  for (int k = 0; k < RANK; ++k) a[k] = lora_a[(size_t)id[0] * RANK + k];

#pragma unroll
  for (int i = 0; i < TOKENS_PER_BLOCK; ++i) {
    const int ip = min(i + 1, TOKENS_PER_BLOCK - 1);
    const float4 e_next = *reinterpret_cast<const float4*>(emb + (size_t)id[ip] * DIM + c4);
    float a_next[RANK];
#pragma unroll
    for (int k = 0; k < RANK; ++k) a_next[k] = lora_a[(size_t)id[ip] * RANK + k];

    float dx = 0.f, dy = 0.f, dz = 0.f, dw = 0.f;
#pragma unroll
    for (int k = 0; k < RANK; ++k) {
      dx = fmaf(a[k], B[k].x, dx);
      dy = fmaf(a[k], B[k].y, dy);
      dz = fmaf(a[k], B[k].z, dz);
      dw = fmaf(a[k], B[k].w, dw);
    }
    float4 o;
    o.x = fmaf(SCALING, dx, e.x) * sc.x;
    o.y = fmaf(SCALING, dy, e.y) * sc.y;
    o.z = fmaf(SCALING, dz, e.z) * sc.z;
    o.w = fmaf(SCALING, dw, e.w) * sc.w;

    const int tok = tok0 + i;
    if (tok < n_tokens)
      *reinterpret_cast<float4*>(out + (size_t)tok * DIM + c4) = o;

    e = e_next;
#pragma unroll
    for (int k = 0; k < RANK; ++k) a[k] = a_next[k];
  }
}

extern "C" void kernel_launch(void* const* d_in, const int* in_sizes, int n_in,
                              void* d_out, int out_size, void* d_ws, size_t ws_size,
                              hipStream_t stream) {
  const int*   tokens    = (const int*)d_in[0];    // [8,2048] int32
  const float* emb       = (const float*)d_in[1];  // [V, D]
  const float* lora_a    = (const float*)d_in[2];  // [V, R]
  const float* lora_b    = (const float*)d_in[3];  // [R, D]
  const float* magnitude = (const float*)d_in[4];  // [D]
  float* out = (float*)d_out;

  const int n_tokens = in_sizes[0];                // 16384

  float* partials = (float*)d_ws;                                  // P1_BLOCKS*DIM floats
  float* scale    = (float*)d_ws + (size_t)P1_BLOCKS * DIM;        // DIM floats

  dora_pass1<<<P1_BLOCKS, P1_THREADS, 0, stream>>>(emb, lora_a, lora_b, partials);
  dora_reduce<<<RED_BLOCKS, RED_THREADS, 0, stream>>>(partials, magnitude, scale);

  const int gather_blocks = (n_tokens + TOKENS_PER_BLOCK - 1) / TOKENS_PER_BLOCK;
  dora_gather<<<gather_blocks, G_THREADS, 0, stream>>>(tokens, emb, lora_a, lora_b,
                                                       scale, out, n_tokens);
}